// Round 2
// baseline (121.119 us; speedup 1.0000x reference)
//
#include <hip/hip_runtime.h>
#include <stdint.h>
#include <stddef.h>

#define Bv 16
#define Cv 256
#define Hv 64
#define Wv 64
#define Kv 1024
#define HWv (Hv * Wv)   // 4096
#define Nv (Bv * HWv)   // 65536

typedef float f32x4 __attribute__((ext_vector_type(4)));
typedef unsigned short u16x4 __attribute__((ext_vector_type(4)));
typedef unsigned short u16x8 __attribute__((ext_vector_type(8)));
typedef __bf16 bf16x8 __attribute__((ext_vector_type(8)));

__device__ __forceinline__ unsigned short f2bf(float f) {
  unsigned u = __builtin_bit_cast(unsigned, f);
  u += 0x7fffu + ((u >> 16) & 1u);   // RNE
  return (unsigned short)(u >> 16);
}

// ---------------- Kernel 1: embedding prep: bf16 copy + ||e_k||^2 ----------
__global__ __launch_bounds__(64) void k_prep(const float* __restrict__ e,
                                             unsigned short* __restrict__ ebf,
                                             float* __restrict__ eq) {
  int k = blockIdx.x;          // 0..1023
  int lane = threadIdx.x;      // 0..63
  const float* row = e + (size_t)k * Cv;
  f32x4 v = *(const f32x4*)(row + lane * 4);
  u16x4 bv = { f2bf(v[0]), f2bf(v[1]), f2bf(v[2]), f2bf(v[3]) };
  *(u16x4*)(ebf + (size_t)k * Cv + lane * 4) = bv;
  float p = v[0]*v[0] + v[1]*v[1] + v[2]*v[2] + v[3]*v[3];
  #pragma unroll
  for (int off = 32; off > 0; off >>= 1) p += __shfl_down(p, off);
  if (lane == 0) eq[k] = p;
}

// ---------------- Fused kernel -------------------------------------------
// Per block: 128 rows (n0 = blk*128; 128 | 4096 so one image b per block).
// Phase 1: z (NCHW) -> LDS tile [64c][128n] per c-chunk -> zp write (fp32,
//          coalesced) + bf16 A-fragments in registers.
// Phase 2: MFMA GEMM S = ||e||^2 - 2 z.e over 16 B-chunks (LDS, XOR swizzle),
//          running argmin in registers.
// Phase 3: cross-lane argmin reduce -> il[] in LDS.
// Phase 4: gather e rows (L2-resident) -> zq coalesced + zout via LDS
//          transpose tile.  (z_out == z_q numerically: STE.)
#define NCHUNK_BYTES (64 * Cv * 2)   // 32768

__global__ __launch_bounds__(256) void k_fused(const float* __restrict__ z,
                                               const float* __restrict__ e,
                                               const unsigned short* __restrict__ ebf,
                                               const float* __restrict__ eq,
                                               float* __restrict__ zout,
                                               float* __restrict__ zq,
                                               float* __restrict__ zp) {
  __shared__ union alignas(16) {
    float t[64][129];                 // 33024 B transpose tile
    unsigned char bl[NCHUNK_BYTES];   // 32768 B GEMM B-chunk
  } sm;
  __shared__ int il[128];

  int tid  = threadIdx.x;
  int lane = tid & 63;
  int wid  = tid >> 6;            // 0..3
  int l15  = lane & 15;
  int l4   = lane >> 4;           // 0..3
  int n0   = blockIdx.x * 128;
  int b    = n0 >> 12;
  int hw0  = n0 & 4095;
  int row0 = wid * 32;            // block-local row base for this wave

  // ================= Phase 1: transpose + zp + A-frags =================
  u16x8 afr[2][8];
  {
    int c_l = tid >> 5;           // 0..7
    int hwq = tid & 31;           // 0..31
    int nq  = tid >> 4;           // 0..15
    int cq  = (tid & 15) * 4;     // 0..60
    #pragma unroll
    for (int cch = 0; cch < 4; ++cch) {
      int c0 = cch * 64;
      // global read z, coalesced along hw; LDS write [c][n]
      #pragma unroll
      for (int it = 0; it < 8; ++it) {
        int c = it * 8 + c_l;
        f32x4 v = *(const f32x4*)(z + ((size_t)(b * Cv + c0 + c)) * HWv + hw0 + hwq * 4);
        sm.t[c][hwq * 4 + 0] = v[0]; sm.t[c][hwq * 4 + 1] = v[1];
        sm.t[c][hwq * 4 + 2] = v[2]; sm.t[c][hwq * 4 + 3] = v[3];
      }
      __syncthreads();
      // zp write: row n, f32x4 along c (2-way bank alias only)
      #pragma unroll
      for (int it = 0; it < 8; ++it) {
        int n = it * 16 + nq;
        f32x4 v = { sm.t[cq][n], sm.t[cq + 1][n], sm.t[cq + 2][n], sm.t[cq + 3][n] };
        *(f32x4*)(zp + (size_t)(n0 + n) * Cv + c0 + cq) = v;
      }
      // A-fragments for this 64-c chunk: k = cc*32 + l4*8 + j
      #pragma unroll
      for (int rt = 0; rt < 2; ++rt) {
        int n = row0 + rt * 16 + l15;
        #pragma unroll
        for (int sub = 0; sub < 2; ++sub) {
          int cl0 = sub * 32 + l4 * 8;
          u16x8 a;
          #pragma unroll
          for (int j = 0; j < 8; ++j) a[j] = f2bf(sm.t[cl0 + j][n]);
          afr[rt][cch * 2 + sub] = a;
        }
      }
      __syncthreads();   // tile consumed; safe to overwrite
    }
  }

  // ================= Phase 2: GEMM + running argmin =====================
  float minv[2][4];
  int   mini[2][4];
  #pragma unroll
  for (int rt = 0; rt < 2; ++rt)
    #pragma unroll
    for (int j = 0; j < 4; ++j) { minv[rt][j] = 3.0e38f; mini[rt][j] = 0; }

  int swz = (lane & 7) << 4;

  for (int nc = 0; nc < 16; ++nc) {
    // stage B chunk: linear global read, swizzled LDS write
    const unsigned char* src = (const unsigned char*)ebf + (size_t)nc * NCHUNK_BYTES;
    #pragma unroll
    for (int it = 0; it < 8; ++it) {
      int p = tid * 16 + it * 4096;
      u16x8 v = *(const u16x8*)(src + p);
      int q = p ^ (((p >> 9) & 7) << 4);
      *(u16x8*)(sm.bl + q) = v;
    }
    __syncthreads();   // chunk visible to all waves

    #pragma unroll
    for (int ct = 0; ct < 4; ++ct) {
      int col = nc * 64 + ct * 16 + l15;
      float eqv = eq[col];
      int rb = (ct * 16 + l15) * 512;   // row stride 512 B
      u16x8 bfr[8];
      #pragma unroll
      for (int cc = 0; cc < 8; ++cc) {
        int off = (l4 * 16 + cc * 64) ^ swz;
        bfr[cc] = *(const u16x8*)(sm.bl + rb + off);
      }
      #pragma unroll
      for (int rt = 0; rt < 2; ++rt) {
        f32x4 acc = { 0.f, 0.f, 0.f, 0.f };
        #pragma unroll
        for (int cc = 0; cc < 8; ++cc)
          acc = __builtin_amdgcn_mfma_f32_16x16x32_bf16(
                  __builtin_bit_cast(bf16x8, afr[rt][cc]),
                  __builtin_bit_cast(bf16x8, bfr[cc]), acc, 0, 0, 0);
        #pragma unroll
        for (int j = 0; j < 4; ++j) {
          float s = fmaf(-2.0f, acc[j], eqv);
          // cols ascend -> strict '<' keeps lowest index (np.argmin semantics)
          if (s < minv[rt][j]) { minv[rt][j] = s; mini[rt][j] = col; }
        }
      }
    }
    __syncthreads();   // chunk fully consumed before overwrite
  }

  // ================= Phase 3: argmin reduce -> il[] =====================
  #pragma unroll
  for (int rt = 0; rt < 2; ++rt) {
    #pragma unroll
    for (int j = 0; j < 4; ++j) {
      float v = minv[rt][j];
      int   ix = mini[rt][j];
      #pragma unroll
      for (int off = 1; off < 16; off <<= 1) {
        float ov = __shfl_xor(v, off);
        int   oi = __shfl_xor(ix, off);
        if (ov < v || (ov == v && oi < ix)) { v = ov; ix = oi; }
      }
      if (l15 == 0) il[row0 + rt * 16 + l4 * 4 + j] = ix;
    }
  }
  __syncthreads();

  // ================= Phase 4: gather -> zq + zout =======================
  {
    int nq  = tid >> 4;           // 0..15
    int cq  = (tid & 15) * 4;
    int c_l = tid >> 5;           // 0..7
    int hwq = tid & 31;
    #pragma unroll
    for (int cch = 0; cch < 4; ++cch) {
      int c0 = cch * 64;
      #pragma unroll
      for (int it = 0; it < 8; ++it) {
        int n = it * 16 + nq;
        f32x4 v = *(const f32x4*)(e + (size_t)il[n] * Cv + c0 + cq);
        *(f32x4*)(zq + (size_t)(n0 + n) * Cv + c0 + cq) = v;
        sm.t[cq + 0][n] = v[0]; sm.t[cq + 1][n] = v[1];
        sm.t[cq + 2][n] = v[2]; sm.t[cq + 3][n] = v[3];
      }
      __syncthreads();
      #pragma unroll
      for (int it = 0; it < 8; ++it) {
        int c = it * 8 + c_l;
        f32x4 v = { sm.t[c][hwq * 4 + 0], sm.t[c][hwq * 4 + 1],
                    sm.t[c][hwq * 4 + 2], sm.t[c][hwq * 4 + 3] };
        *(f32x4*)(zout + ((size_t)(b * Cv + c0 + c)) * HWv + hw0 + hwq * 4) = v;
      }
      __syncthreads();   // protect tile before next chunk overwrites
    }
  }
}

// ---------------------------------------------------------------------------
extern "C" void kernel_launch(void* const* d_in, const int* in_sizes, int n_in,
                              void* d_out, int out_size, void* d_ws, size_t ws_size,
                              hipStream_t stream) {
  const float* z = (const float*)d_in[0];            // [16,256,64,64]
  const float* e = (const float*)d_in[1];            // [1024,256]

  float* out0 = (float*)d_out;                       // z_out  NCHW
  float* out1 = out0 + (size_t)Nv * Cv;              // z_q    [N][C]
  float* out2 = out1 + (size_t)Nv * Cv;              // zp     [N][C]

  const size_t EBF_B = (size_t)Kv * Cv * 2;          // 524288
  const size_t EQ_B  = (size_t)Kv * 4;               // 4096
  if (ws_size < EBF_B + EQ_B) return;
  unsigned short* ebf = (unsigned short*)d_ws;
  float* eq = (float*)((char*)d_ws + EBF_B);

  k_prep<<<Kv, 64, 0, stream>>>(e, ebf, eq);
  k_fused<<<Nv / 128, 256, 0, stream>>>(z, e, ebf, eq, out0, out1, out2);
}

// Round 3
// 99.537 us; speedup vs baseline: 1.2168x; 1.2168x over previous
//
#include <hip/hip_runtime.h>
#include <stdint.h>
#include <stddef.h>

#define Bv 16
#define Cv 256
#define Hv 64
#define Wv 64
#define Kv 1024
#define HWv (Hv * Wv)   // 4096
#define Nv (Bv * HWv)   // 65536

typedef float f32x4 __attribute__((ext_vector_type(4)));
typedef unsigned short u16x4 __attribute__((ext_vector_type(4)));
typedef unsigned short u16x8 __attribute__((ext_vector_type(8)));
typedef __bf16 bf16x8 __attribute__((ext_vector_type(8)));

__device__ __forceinline__ unsigned short f2bf(float f) {
  unsigned u = __builtin_bit_cast(unsigned, f);
  u += 0x7fffu + ((u >> 16) & 1u);   // RNE
  return (unsigned short)(u >> 16);
}

// ---------------- Kernel 1: embedding prep: bf16 copy + ||e_k||^2 ----------
__global__ __launch_bounds__(64) void k_prep(const float* __restrict__ e,
                                             unsigned short* __restrict__ ebf,
                                             float* __restrict__ eq) {
  int k = blockIdx.x;          // 0..1023
  int lane = threadIdx.x;      // 0..63
  const float* row = e + (size_t)k * Cv;
  f32x4 v = *(const f32x4*)(row + lane * 4);
  u16x4 bv = { f2bf(v[0]), f2bf(v[1]), f2bf(v[2]), f2bf(v[3]) };
  *(u16x4*)(ebf + (size_t)k * Cv + lane * 4) = bv;
  float p = v[0]*v[0] + v[1]*v[1] + v[2]*v[2] + v[3]*v[3];
  #pragma unroll
  for (int off = 32; off > 0; off >>= 1) p += __shfl_down(p, off);
  if (lane == 0) eq[k] = p;
}

// ---------------- Kernel 2: z (NCHW) -> zp (NHWC flat [N][C]) --------------
// (unchanged from R1 — independent of the GEMM now)
__global__ __launch_bounds__(256) void k_transpose(const float* __restrict__ z,
                                                   float* __restrict__ zp) {
  __shared__ float t[64][65];
  int tn = blockIdx.x & 1023;
  int tc = blockIdx.x >> 10;      // 0..3
  int n0 = tn * 64;
  int b  = n0 >> 12;
  int hw0 = n0 & 4095;
  int c0 = tc * 64;
  int tid = threadIdx.x;

  int cl  = tid >> 4;             // 0..15
  int hw4 = (tid & 15) * 4;
  #pragma unroll
  for (int p = 0; p < 4; ++p) {
    int c = p * 16 + cl;
    f32x4 v = *(const f32x4*)(z + ((size_t)b * Cv + (c0 + c)) * HWv + hw0 + hw4);
    t[c][hw4 + 0] = v[0]; t[c][hw4 + 1] = v[1];
    t[c][hw4 + 2] = v[2]; t[c][hw4 + 3] = v[3];
  }
  __syncthreads();

  int nl = tid >> 2;              // 0..63
  int cb = (tid & 3) * 4;
  float* orow = zp + (size_t)(n0 + nl) * Cv + c0;
  #pragma unroll
  for (int q = 0; q < 4; ++q) {
    int c = cb + q * 16;
    f32x4 v = { t[c][nl], t[c + 1][nl], t[c + 2][nl], t[c + 3][nl] };
    *(f32x4*)(orow + c) = v;
  }
}

// ---------------- Kernel 3: GEMM + argmin + gather (fused tail) ------------
// Per block: 128 rows. A-fragments loaded DIRECTLY from z (NCHW): for frag
// element j (channel c), lanes l15 = consecutive hw -> 64B segments. No zp
// dependency. B (ebf) streamed through 32KB LDS chunks (XOR swizzle) with a
// one-chunk register prefetch so global latency hides under MFMA. After the
// argmin reduce, the same block gathers e rows -> zq + zout (LDS reused as
// the transpose tile).
#define NCHUNK_BYTES (64 * Cv * 2)   // 32768

__global__ __launch_bounds__(256) void k_gg(const float* __restrict__ z,
                                            const float* __restrict__ e,
                                            const unsigned short* __restrict__ ebf,
                                            const float* __restrict__ eq,
                                            float* __restrict__ zout,
                                            float* __restrict__ zq) {
  __shared__ union alignas(16) {
    float t[64][129];                 // gather transpose tile (33024 B)
    unsigned char bl[NCHUNK_BYTES];   // GEMM B-chunk (32768 B)
  } sm;
  __shared__ int il[128];

  int tid  = threadIdx.x;
  int lane = tid & 63;
  int wid  = tid >> 6;            // 0..3
  int l15  = lane & 15;
  int l4   = lane >> 4;           // 0..3
  int n0   = blockIdx.x * 128;
  int b    = n0 >> 12;
  int hw0  = n0 & 4095;
  int row0 = wid * 32;            // block-local row base for this wave

  // ---- A-fragments straight from z (one-time head) ----
  // afr[rt][cc][j] = bf16( z[b][cc*32 + l4*8 + j][hw0 + row0 + rt*16 + l15] )
  u16x8 afr[2][8];
  #pragma unroll
  for (int rt = 0; rt < 2; ++rt) {
    const float* zr = z + (size_t)b * Cv * HWv + hw0 + row0 + rt * 16 + l15;
    #pragma unroll
    for (int cc = 0; cc < 8; ++cc) {
      int cbase = cc * 32 + l4 * 8;
      u16x8 a;
      #pragma unroll
      for (int j = 0; j < 8; ++j)
        a[j] = f2bf(zr[(size_t)(cbase + j) * HWv]);
      afr[rt][cc] = a;
    }
  }

  // ---- prefetch chunk 0 into registers ----
  u16x8 stg[8];
  {
    const unsigned char* src = (const unsigned char*)ebf;
    #pragma unroll
    for (int it = 0; it < 8; ++it)
      stg[it] = *(const u16x8*)(src + tid * 16 + it * 4096);
  }

  float minv[2][4];
  int   mini[2][4];
  #pragma unroll
  for (int rt = 0; rt < 2; ++rt)
    #pragma unroll
    for (int j = 0; j < 4; ++j) { minv[rt][j] = 3.0e38f; mini[rt][j] = 0; }

  int swz = (lane & 7) << 4;

  for (int nc = 0; nc < 16; ++nc) {
    __syncthreads();   // previous chunk fully consumed (no-op at nc==0)
    // write prefetched chunk to LDS (swizzled)
    #pragma unroll
    for (int it = 0; it < 8; ++it) {
      int p = tid * 16 + it * 4096;
      int q = p ^ (((p >> 9) & 7) << 4);
      *(u16x8*)(sm.bl + q) = stg[it];
    }
    __syncthreads();   // chunk visible to all waves
    // issue next chunk's loads now; vmcnt waited at next iteration's write,
    // hidden under this chunk's ds_read+MFMA work
    if (nc < 15) {
      const unsigned char* src = (const unsigned char*)ebf + (size_t)(nc + 1) * NCHUNK_BYTES;
      #pragma unroll
      for (int it = 0; it < 8; ++it)
        stg[it] = *(const u16x8*)(src + tid * 16 + it * 4096);
    }

    #pragma unroll
    for (int ct = 0; ct < 4; ++ct) {
      int col = nc * 64 + ct * 16 + l15;
      float eqv = eq[col];
      int rb = (ct * 16 + l15) * 512;   // row stride 512 B
      u16x8 bfr[8];
      #pragma unroll
      for (int cc = 0; cc < 8; ++cc) {
        int off = (l4 * 16 + cc * 64) ^ swz;
        bfr[cc] = *(const u16x8*)(sm.bl + rb + off);
      }
      #pragma unroll
      for (int rt = 0; rt < 2; ++rt) {
        f32x4 acc = { 0.f, 0.f, 0.f, 0.f };
        #pragma unroll
        for (int cc = 0; cc < 8; ++cc)
          acc = __builtin_amdgcn_mfma_f32_16x16x32_bf16(
                  __builtin_bit_cast(bf16x8, afr[rt][cc]),
                  __builtin_bit_cast(bf16x8, bfr[cc]), acc, 0, 0, 0);
        #pragma unroll
        for (int j = 0; j < 4; ++j) {
          float s = fmaf(-2.0f, acc[j], eqv);
          // cols ascend -> strict '<' keeps lowest index (np.argmin semantics)
          if (s < minv[rt][j]) { minv[rt][j] = s; mini[rt][j] = col; }
        }
      }
    }
  }

  // ---- argmin reduce across the 16 col-lanes -> il[] ----
  #pragma unroll
  for (int rt = 0; rt < 2; ++rt) {
    #pragma unroll
    for (int j = 0; j < 4; ++j) {
      float v = minv[rt][j];
      int   ix = mini[rt][j];
      #pragma unroll
      for (int off = 1; off < 16; off <<= 1) {
        float ov = __shfl_xor(v, off);
        int   oi = __shfl_xor(ix, off);
        if (ov < v || (ov == v && oi < ix)) { v = ov; ix = oi; }
      }
      if (l15 == 0) il[row0 + rt * 16 + l4 * 4 + j] = ix;
    }
  }
  __syncthreads();   // il visible; all waves done reading sm.bl

  // ---- gather tail: e rows -> zq (coalesced) + zout (LDS transpose) ----
  {
    int nq  = tid >> 4;           // 0..15
    int cq  = (tid & 15) * 4;
    int c_l = tid >> 5;           // 0..7
    int hwq = tid & 31;
    #pragma unroll
    for (int cch = 0; cch < 4; ++cch) {
      int c0 = cch * 64;
      #pragma unroll
      for (int it = 0; it < 8; ++it) {
        int n = it * 16 + nq;
        f32x4 v = *(const f32x4*)(e + (size_t)il[n] * Cv + c0 + cq);
        *(f32x4*)(zq + (size_t)(n0 + n) * Cv + c0 + cq) = v;
        sm.t[cq + 0][n] = v[0]; sm.t[cq + 1][n] = v[1];
        sm.t[cq + 2][n] = v[2]; sm.t[cq + 3][n] = v[3];
      }
      __syncthreads();
      #pragma unroll
      for (int it = 0; it < 8; ++it) {
        int c = it * 8 + c_l;
        f32x4 v = { sm.t[c][hwq * 4 + 0], sm.t[c][hwq * 4 + 1],
                    sm.t[c][hwq * 4 + 2], sm.t[c][hwq * 4 + 3] };
        *(f32x4*)(zout + ((size_t)(b * Cv + c0 + c)) * HWv + hw0 + hwq * 4) = v;
      }
      __syncthreads();   // protect tile before next chunk overwrites
    }
  }
}

// ---------------------------------------------------------------------------
extern "C" void kernel_launch(void* const* d_in, const int* in_sizes, int n_in,
                              void* d_out, int out_size, void* d_ws, size_t ws_size,
                              hipStream_t stream) {
  const float* z = (const float*)d_in[0];            // [16,256,64,64]
  const float* e = (const float*)d_in[1];            // [1024,256]

  float* out0 = (float*)d_out;                       // z_out  NCHW
  float* out1 = out0 + (size_t)Nv * Cv;              // z_q    [N][C]
  float* out2 = out1 + (size_t)Nv * Cv;              // zp     [N][C]

  const size_t EBF_B = (size_t)Kv * Cv * 2;          // 524288
  const size_t EQ_B  = (size_t)Kv * 4;               // 4096
  if (ws_size < EBF_B + EQ_B) return;
  unsigned short* ebf = (unsigned short*)d_ws;
  float* eq = (float*)((char*)d_ws + EBF_B);

  k_prep<<<Kv, 64, 0, stream>>>(e, ebf, eq);
  k_gg<<<Nv / 128, 256, 0, stream>>>(z, e, ebf, eq, out0, out1);
  k_transpose<<<(Nv / 64) * (Cv / 64), 256, 0, stream>>>(z, out2);
}